// Round 4
// baseline (2596.397 us; speedup 1.0000x reference)
//
#include <hip/hip_runtime.h>
#include <math.h>

// B=2,H=16,S=1024,D=64 attention with additive biases + mask -> -1e9.
// Outputs context (B,H,S,D) and attn (B,H,S,S), f32.
//
// R6 = R2 structure (256 thr, 16 q-rows, 72 KB LDS, PV from LDS) with the
// K-staging stall removed:
//  * K tile row-major KBUF[half][256][8]f4, XOR-swizzled (dq^((k>>2)&7)) ->
//    FMA-side ds_read_b128 is bank-balanced AND the LDS dest is linear, so
//    staging uses __builtin_amdgcn_global_load_lds (16B, zero VGPRs, global
//    src pre-swizzled per-lane).
//  * Double-buffered d-halves; DMA for half t+1/t+2 issued a full FMA-half
//    (~512 FMAs) ahead; raw s_barrier + counted s_waitcnt vmcnt(8) keep the
//    loads in flight across barriers (no __syncthreads full drain in-loop).
//  * VGPR discipline: no staging registers at all; launch_bounds (256,2)
//    (empirical: cap = 256/arg2; 128 needed, 64 spills catastrophically).
// Occupancy stays 8 waves/CU by design (VGPR 128 tier) - this round attacks
// the exposed latency, not occupancy.
#define S_LEN 1024
#define D_DIM 64
#define NEGV  (-1.0e9f)

__device__ __forceinline__ void gll16(const void* g, void* l) {
    __builtin_amdgcn_global_load_lds(
        (const __attribute__((address_space(1))) void*)g,
        (__attribute__((address_space(3))) void*)l, 16, 0, 0);
}

// acc += dot(qv, kv), d-ascending (innermost = lowest d, matches R2 order)
#define DOT4(ACC, QV, KV)                                                      \
    ACC = fmaf((QV).w, (KV).w,                                                 \
          fmaf((QV).z, (KV).z,                                                 \
          fmaf((QV).y, (KV).y,                                                 \
          fmaf((QV).x, (KV).x, (ACC)))))

__global__ __launch_bounds__(256, 2)
void attn_bias_fused(const float* __restrict__ Q, const float* __restrict__ K,
                     const float* __restrict__ V, const int* __restrict__ mif,
                     const float* __restrict__ iat, const float* __restrict__ iaf,
                     float* __restrict__ ctx, float* __restrict__ attn)
{
    // 64 KB: two 32-KB K half-tiles (row-major, swizzled); reused as Pn[16][1024].
    __shared__ float4 KBUF[2][256][8];
    // 8 KB: Qst[16][64] (4 KB) during QK; scratch[4][8][64] during PV reduce.
    __shared__ float  SB[2048];

    float (*Qst)[64] = (float(*)[64])SB;
    float* Pn  = (float*)KBUF;           // [16][1024]
    float* scr = SB;

    const int tid  = threadIdx.x;
    const int wave = tid >> 6;            // 0..3
    const int lane = tid & 63;

    // XCD-aware swizzle (2048 = 8*256, bijective): each XCD gets 4 bh values;
    // K+V (2 MB) stay L2-resident for the 64 q-tiles that share them.
    const int blk = blockIdx.x;
    const int swz = ((blk & 7) << 8) | (blk >> 3);
    const int bh  = swz >> 6;             // 0..31
    const int qb  = (swz & 63) << 4;      // 16-row q tile

    const float* Qb = Q + ((size_t)(bh * S_LEN + qb)) * D_DIM;
    const float* Kb = K + ((size_t)bh * S_LEN) * D_DIM;
    const float* Vb = V + ((size_t)bh * S_LEN) * D_DIM;

    const int kg = lane;   // k-quad owner within the 256-k chunk
    const int qg = wave;   // 4 q rows per wave

    // ---- issue K DMA for half (CN,HH) into KBUF[HH]; 8 instrs/wave, 0 VGPR held
    #define GLL_HALF(CN, HH)                                                   \
        {                                                                      \
            const float* gb_ = Kb + (((size_t)(CN) * 256) << 6) + (HH) * 32;   \
            _Pragma("unroll")                                                  \
            for (int j_ = 0; j_ < 8; ++j_) {                                   \
                int kk_ = (wave << 6) + (j_ << 3) + (lane >> 3);               \
                int dq_ = (lane & 7) ^ ((kk_ >> 2) & 7);                       \
                gll16(gb_ + (((size_t)kk_) << 6) + (dq_ << 2),                 \
                      (void*)&KBUF[HH][(wave << 6) + (j_ << 3)][0]);           \
            }                                                                  \
        }

    // ---- one d-half of QK^T: 8 dq steps x (4 K b128 + 4 Q broadcast + 64 fma)
    #define FMA_HALF(HH)                                                       \
        _Pragma("unroll")                                                      \
        for (int dq = 0; dq < 8; ++dq) {                                       \
            const int ci_ = dq ^ (kg & 7);                                     \
            float4 k0 = KBUF[HH][4 * kg + 0][ci_];                             \
            float4 k1 = KBUF[HH][4 * kg + 1][ci_];                             \
            float4 k2 = KBUF[HH][4 * kg + 2][ci_];                             \
            float4 k3 = KBUF[HH][4 * kg + 3][ci_];                             \
            const float* qp_ = &Qst[qg * 4][(HH) * 32 + dq * 4];               \
            float4 q0 = *(const float4*)(qp_);                                 \
            float4 q1 = *(const float4*)(qp_ + 64);                            \
            float4 q2 = *(const float4*)(qp_ + 128);                           \
            float4 q3 = *(const float4*)(qp_ + 192);                           \
            DOT4(a0.x, q0, k0); DOT4(a0.y, q0, k1);                            \
            DOT4(a0.z, q0, k2); DOT4(a0.w, q0, k3);                            \
            DOT4(a1.x, q1, k0); DOT4(a1.y, q1, k1);                            \
            DOT4(a1.z, q1, k2); DOT4(a1.w, q1, k3);                            \
            DOT4(a2.x, q2, k0); DOT4(a2.y, q2, k1);                            \
            DOT4(a2.z, q2, k2); DOT4(a2.w, q2, k3);                            \
            DOT4(a3.x, q3, k0); DOT4(a3.y, q3, k1);                            \
            DOT4(a3.z, q3, k2); DOT4(a3.w, q3, k3);                            \
        }

    // ---- prologue: stage Q (row-major, no transpose) + first two K halves
    {
        int q = tid >> 4, l = tid & 15;
        float4 v = *(const float4*)(Qb + (size_t)q * D_DIM + l * 4);
        *(float4*)&Qst[q][l * 4] = v;
    }
    GLL_HALF(0, 0);
    GLL_HALF(0, 1);
    asm volatile("s_waitcnt vmcnt(8) lgkmcnt(0)" ::: "memory");  // H(0,0)+Qst ready
    __builtin_amdgcn_s_barrier();

    float4 sc[16];         // sc[c*4+i]: row qg*4+i, k = c*256 + kg*4 .. +3

    // =================== QK^T + bias + mask -> registers ===================
    // Invariant at loop top: KBUF[0] = H(c,0) valid for all waves; H(c,1) DMA
    // in flight (8 outstanding).
    #pragma unroll
    for (int c = 0; c < 4; ++c) {
        float4 a0 = {0.f, 0.f, 0.f, 0.f}, a1 = a0, a2 = a0, a3 = a0;

        FMA_HALF(0);                                   // reads H(c,0)
        asm volatile("s_waitcnt lgkmcnt(0)" ::: "memory");
        __builtin_amdgcn_s_barrier();                  // B1: KBUF[0] readers done
        if (c < 3) {
            GLL_HALF(c + 1, 0);                        // next even half -> KBUF[0]
            asm volatile("s_waitcnt vmcnt(8)" ::: "memory");   // H(c,1) complete
        } else {
            asm volatile("s_waitcnt vmcnt(0)" ::: "memory");   // H(3,1) complete
        }
        __builtin_amdgcn_s_barrier();                  // B2: H(c,1) certified

        // bias/mask for this chunk: issued before the second FMA half, consumed
        // after it (one FMA-half ~ >=1024 cyc of cover).
        float4 bt[4], bf[4];
        int4   bm[4];
        #pragma unroll
        for (int i = 0; i < 4; ++i) {
            size_t off = ((size_t)(bh * S_LEN + qb + qg * 4 + i)) * S_LEN
                       + c * 256 + kg * 4;
            bt[i] = *(const float4*)(iat + off);
            bf[i] = *(const float4*)(iaf + off);
            bm[i] = *(const int4*)(mif + off);
        }

        FMA_HALF(1);                                   // reads H(c,1)
        asm volatile("s_waitcnt vmcnt(0)" ::: "memory");  // bias + H(c+1,0) done

        {
            float4 av[4] = {a0, a1, a2, a3};
            #pragma unroll
            for (int i = 0; i < 4; ++i) {
                float4 s = av[i];
                float4 t = bt[i], f = bf[i];
                int4   m = bm[i];
                s.x = m.x ? NEGV : fmaf(s.x, 0.125f, t.x + f.x);
                s.y = m.y ? NEGV : fmaf(s.y, 0.125f, t.y + f.y);
                s.z = m.z ? NEGV : fmaf(s.z, 0.125f, t.z + f.z);
                s.w = m.w ? NEGV : fmaf(s.w, 0.125f, t.w + f.w);
                sc[c * 4 + i] = s;
            }
        }

        asm volatile("s_waitcnt lgkmcnt(0)" ::: "memory");
        __builtin_amdgcn_s_barrier();                  // B1': KBUF[1] readers done
        if (c < 3) GLL_HALF(c + 1, 1);                 // next odd half -> KBUF[1]
    }
    // Final barrier above (B1' at c=3) certifies all KBUF reads done ->
    // safe to reuse as Pn.

    // =================== softmax in registers (64-lane shuffles) ===================
    {
        float mx[4], rinv[4];
        #pragma unroll
        for (int i = 0; i < 4; ++i) {
            float m = -INFINITY;
            #pragma unroll
            for (int c = 0; c < 4; ++c) {
                float4 v = sc[c * 4 + i];
                m = fmaxf(m, fmaxf(fmaxf(v.x, v.y), fmaxf(v.z, v.w)));
            }
            #pragma unroll
            for (int s = 1; s < 64; s <<= 1) m = fmaxf(m, __shfl_xor(m, s, 64));
            mx[i] = m;
        }
        #pragma unroll
        for (int i = 0; i < 4; ++i) {
            float sm = 0.f;
            #pragma unroll
            for (int c = 0; c < 4; ++c) {
                float4 v = sc[c * 4 + i];
                v.x = __expf(v.x - mx[i]);   // all-masked row -> exp(0)=1 -> uniform, matches ref
                v.y = __expf(v.y - mx[i]);
                v.z = __expf(v.z - mx[i]);
                v.w = __expf(v.w - mx[i]);
                sc[c * 4 + i] = v;
                sm += v.x + v.y + v.z + v.w;
            }
            #pragma unroll
            for (int s = 1; s < 64; s <<= 1) sm += __shfl_xor(sm, s, 64);
            rinv[i] = 1.f / sm;
        }
        // normalize; write attn (coalesced 1 KiB/row) + Pn (LDS, stride-16B free)
        #pragma unroll
        for (int i = 0; i < 4; ++i) {
            int r = qg * 4 + i;
            float* arow = attn + ((size_t)(bh * S_LEN + qb + r)) * S_LEN;
            #pragma unroll
            for (int c = 0; c < 4; ++c) {
                float4 v = sc[c * 4 + i];
                v.x *= rinv[i]; v.y *= rinv[i]; v.z *= rinv[i]; v.w *= rinv[i];
                *(float4*)(arow + c * 256 + kg * 4)      = v;
                *(float4*)&Pn[r * 1024 + c * 256 + kg * 4] = v;
            }
        }
    }
    __syncthreads();   // Pn complete for all rows

    // =================== context = P @ V (P from LDS) ===================
    // Wave w covers k in [w*256,(w+1)*256) for ALL 16 q rows (V read once/block).
    {
        const int dg = lane & 15;
        const int ks = lane >> 4;
        float4 acc[16];
        #pragma unroll
        for (int q = 0; q < 16; ++q) acc[q] = make_float4(0.f, 0.f, 0.f, 0.f);

        #pragma unroll 2
        for (int i = 0; i < 16; ++i) {
            int k0 = wave * 256 + i * 16 + ks * 4;
            const float* vrow = Vb + (size_t)k0 * D_DIM + dg * 4;
            float4 v0 = *(const float4*)(vrow + 0 * D_DIM);
            float4 v1 = *(const float4*)(vrow + 1 * D_DIM);
            float4 v2 = *(const float4*)(vrow + 2 * D_DIM);
            float4 v3 = *(const float4*)(vrow + 3 * D_DIM);
            #pragma unroll
            for (int q = 0; q < 16; ++q) {
                float4 p = *(const float4*)&Pn[q * 1024 + k0];   // 4-addr broadcast
                float4 a = acc[q];
                a.x = fmaf(p.x, v0.x, a.x); a.x = fmaf(p.y, v1.x, a.x);
                a.x = fmaf(p.z, v2.x, a.x); a.x = fmaf(p.w, v3.x, a.x);
                a.y = fmaf(p.x, v0.y, a.y); a.y = fmaf(p.y, v1.y, a.y);
                a.y = fmaf(p.z, v2.y, a.y); a.y = fmaf(p.w, v3.y, a.y);
                a.z = fmaf(p.x, v0.z, a.z); a.z = fmaf(p.y, v1.z, a.z);
                a.z = fmaf(p.z, v2.z, a.z); a.z = fmaf(p.w, v3.z, a.z);
                a.w = fmaf(p.x, v0.w, a.w); a.w = fmaf(p.y, v1.w, a.w);
                a.w = fmaf(p.z, v2.w, a.w); a.w = fmaf(p.w, v3.w, a.w);
                acc[q] = a;
            }
        }

        // reduce the 4 ks-groups within the wave (xor 16, 32); lanes 0..15 complete
        #pragma unroll
        for (int q = 0; q < 16; ++q) {
            acc[q].x += __shfl_xor(acc[q].x, 16, 64);
            acc[q].y += __shfl_xor(acc[q].y, 16, 64);
            acc[q].z += __shfl_xor(acc[q].z, 16, 64);
            acc[q].w += __shfl_xor(acc[q].w, 16, 64);
            acc[q].x += __shfl_xor(acc[q].x, 32, 64);
            acc[q].y += __shfl_xor(acc[q].y, 32, 64);
            acc[q].z += __shfl_xor(acc[q].z, 32, 64);
            acc[q].w += __shfl_xor(acc[q].w, 32, 64);
        }

        // cross-wave reduction through 8 KB scratch (aliases dead Qst), 2 passes
        #pragma unroll
        for (int qh = 0; qh < 2; ++qh) {
            __syncthreads();   // scratch free (Qst dead / previous pass read done)
            if (lane < 16) {
                #pragma unroll
                for (int j = 0; j < 8; ++j)
                    *(float4*)&scr[(wave * 8 + j) * 64 + dg * 4] = acc[qh * 8 + j];
            }
            __syncthreads();
            if (tid < 128) {
                int qq = tid >> 4;           // 0..7
                int dr = tid & 15;
                float4 r = make_float4(0.f, 0.f, 0.f, 0.f);
                #pragma unroll
                for (int s = 0; s < 4; ++s) {
                    float4 v = *(const float4*)&scr[(s * 8 + qq) * 64 + dr * 4];
                    r.x += v.x; r.y += v.y; r.z += v.z; r.w += v.w;
                }
                *(float4*)(ctx + ((size_t)(bh * S_LEN + qb + qh * 8 + qq)) * D_DIM + dr * 4) = r;
            }
        }
    }
    #undef GLL_HALF
    #undef FMA_HALF
}

extern "C" void kernel_launch(void* const* d_in, const int* in_sizes, int n_in,
                              void* d_out, int out_size, void* d_ws, size_t ws_size,
                              hipStream_t stream) {
    const float* Q   = (const float*)d_in[0];
    const float* K   = (const float*)d_in[1];
    const float* V   = (const float*)d_in[2];
    const int*   mif = (const int*)d_in[4];    // attn_mask_if
    const float* iat = (const float*)d_in[5];
    const float* iaf = (const float*)d_in[6];

    float* ctx  = (float*)d_out;
    float* attn = (float*)d_out + (size_t)2 * 16 * 1024 * 64;

    dim3 grid(2048), block(256);
    hipLaunchKernelGGL(attn_bias_fused, grid, block, 0, stream,
                       Q, K, V, mif, iat, iaf, ctx, attn);
}